// Round 7
// baseline (413.335 us; speedup 1.0000x reference)
//
#include <hip/hip_runtime.h>
#include <hip/hip_bf16.h>
#include <stdint.h>

#define B_SZ 4
#define C_IN 256
#define N_SP 4096
#define HEADS 4
#define DH 32
#define HID 128

#define BI 128      // queries per block (4 waves x 32)
#define BJ 64       // keys per inner tile
#define JH 2048     // keys per block (j-split half)
#define PP 68       // P LDS row pitch in shorts (136 B)

typedef short short4v __attribute__((ext_vector_type(4)));
typedef short short8 __attribute__((ext_vector_type(8)));
typedef float f32x4 __attribute__((ext_vector_type(4)));

#if __has_builtin(__builtin_amdgcn_exp2f)
#define EXP2 __builtin_amdgcn_exp2f
#else
#define EXP2 exp2f
#endif

__device__ __forceinline__ short f2bfs(float f) {  // round-half-up f32->bf16
  return (short)((__float_as_uint(f) + 0x8000u) >> 16);
}
__device__ __forceinline__ uint32_t pk_bf(float a, float b) {  // pack 2 bf16 (a=low)
  uint32_t ua = __float_as_uint(a) + 0x8000u;
  uint32_t ub = __float_as_uint(b) + 0x8000u;
  return (ua >> 16) | (ub & 0xffff0000u);
}
__device__ __forceinline__ short8 ld_frag(const short* p) {  // 8B-aligned 16B LDS read
  short4v a = *(const short4v*)p;
  short4v b = *(const short4v*)(p + 4);
  return __builtin_shufflevector(a, b, 0, 1, 2, 3, 4, 5, 6, 7);
}
__device__ __forceinline__ f32x4 mfma16(short8 a, short8 b, f32x4 c) {
  return __builtin_amdgcn_mfma_f32_16x16x32_bf16(a, b, c, 0, 0, 0);
}

// ---------------- Kernel 1: QKV projection, fused transpose ----------------
// grid (16 nb, 12 og, 4 b). Each block: one 32-row head-section x 256 n.
// Q -> qt[bh][n][32] bf16 (scale*log2e folded), K -> kt[bh][n][32], V -> vt[bh][d][n].
__global__ __launch_bounds__(256) void qkv_proj_k(
    const float* __restrict__ x, const float* __restrict__ w,
    short* __restrict__ qt, short* __restrict__ kt, short* __restrict__ vt) {
  __shared__ short T2[DH * 260];  // [d][n-tile] bf16, pitch 260 shorts
  const int t = threadIdx.x;
  const int tn = t & 63, tr = t >> 6;
  const int nb = blockIdx.x, og = blockIdx.y, b = blockIdx.z;
  const int n0 = nb * 256 + tn * 4;
  const int r0 = og * 32 + tr * 8;  // qkv output row
  const float* xb = x + (size_t)b * C_IN * N_SP + n0;
  float acc[8][4];
#pragma unroll
  for (int r = 0; r < 8; ++r)
#pragma unroll
    for (int j = 0; j < 4; ++j) acc[r][j] = 0.f;
  for (int c = 0; c < C_IN; c += 2) {
    const float4 xa = *(const float4*)(xb + (size_t)c * N_SP);
    const float4 xc = *(const float4*)(xb + (size_t)(c + 1) * N_SP);
    const float xaj[4] = {xa.x, xa.y, xa.z, xa.w};
    const float xcj[4] = {xc.x, xc.y, xc.z, xc.w};
#pragma unroll
    for (int r = 0; r < 8; ++r) {
      const float2 wv = *(const float2*)(w + (size_t)(r0 + r) * C_IN + c);
#pragma unroll
      for (int j = 0; j < 4; ++j) acc[r][j] += wv.x * xaj[j] + wv.y * xcj[j];
    }
  }
  const int sect = og >> 2, h = og & 3;
  const int bh = b * HEADS + h, d0 = tr * 8;
  if (sect == 2) {  // V: [d][n], coalesced 8B stores
#pragma unroll
    for (int r = 0; r < 8; ++r) {
      short4v p;
#pragma unroll
      for (int j = 0; j < 4; ++j) p[j] = f2bfs(acc[r][j]);
      *(short4v*)(vt + ((size_t)bh * DH + d0 + r) * N_SP + n0) = p;
    }
  } else {  // Q/K: LDS [d][n] tile, then chunk-interleaved coalesced [n][d] stores
    const float sc = sect ? 1.f : (0.17677669529663687f * 1.4426950408889634f);
#pragma unroll
    for (int r = 0; r < 8; ++r) {
      short4v p;
#pragma unroll
      for (int j = 0; j < 4; ++j) p[j] = f2bfs(acc[r][j] * sc);
      *(short4v*)(T2 + (d0 + r) * 260 + tn * 4) = p;
    }
    __syncthreads();
    short* dst = (sect ? kt : qt) + ((size_t)bh * N_SP + nb * 256) * DH;
#pragma unroll
    for (int k = 0; k < 4; ++k) {
      const int g = t + 256 * k;          // 16B chunk id, lane-contiguous
      const int n = g >> 2, dq = g & 3;   // row n, d-quarter
      short8 v;
#pragma unroll
      for (int e = 0; e < 8; ++e) v[e] = T2[(dq * 8 + e) * 260 + n];
      *(short8*)(dst + (size_t)g * 8) = v;
    }
  }
}

// ---------------- Kernel 2: flash attention, j-split halves, no-max softmax --------
// grid (32 ib, 16 bh, 2 jh). Unnormalized O -> Oh[jh][bh*32+d][n], l -> lg[jh][bh][n].
__global__ __launch_bounds__(256, 4) void attn_k(
    const short* __restrict__ qt, const short* __restrict__ kt,
    const short* __restrict__ vt, float* __restrict__ Oh, float* __restrict__ lg) {
  __shared__ short Ps[BI * PP];     // 17408 B, [i][j] bf16, rows owned per-wave
  __shared__ float Osh[DH * 132];   // 16896 B, epilogue transpose
  const int t = threadIdx.x;
  const int lane = t & 63, w = t >> 6;
  const int l15 = lane & 15, quad = lane >> 4;
  const int i0 = blockIdx.x * BI;
  const int bh = blockIdx.y, jh = blockIdx.z;
  const int jbeg = jh * JH;
  const short* qg = qt + ((size_t)bh * N_SP + i0) * DH;
  const short* kg = kt + (size_t)bh * N_SP * DH;
  const short* vg = vt + (size_t)bh * DH * N_SP;

  short8 bq[2];
#pragma unroll
  for (int tt = 0; tt < 2; ++tt)
    bq[tt] = *(const short8*)(qg + (size_t)(w * 32 + tt * 16 + l15) * DH + quad * 8);

  const f32x4 zz = {0.f, 0.f, 0.f, 0.f};
  f32x4 o_acc[2][2] = {{zz, zz}, {zz, zz}};  // [tt][dt]
  float lsum[2] = {0.f, 0.f};
  short* prow[2];
#pragma unroll
  for (int tt = 0; tt < 2; ++tt) prow[tt] = Ps + (w * 32 + tt * 16 + l15) * PP;

  short8 akA[4], akB[4], vbA[2][2], vbB[2][2];
#pragma unroll
  for (int jt = 0; jt < 4; ++jt)
    akA[jt] = *(const short8*)(kg + (size_t)(jbeg + jt * 16 + l15) * DH + quad * 8);
#pragma unroll
  for (int dt = 0; dt < 2; ++dt)
#pragma unroll
    for (int kk = 0; kk < 2; ++kk)
      vbA[dt][kk] = *(const short8*)(vg + (size_t)(dt * 16 + l15) * N_SP + jbeg + kk * 32 + quad * 8);

  auto body = [&](const short8 (&akc)[4], const short8 (&vbc)[2][2],
                  short8 (&akn)[4], short8 (&vbn)[2][2], int jn) {
    f32x4 sf[2][4];
#pragma unroll
    for (int tt = 0; tt < 2; ++tt)
#pragma unroll
      for (int jt = 0; jt < 4; ++jt) sf[tt][jt] = mfma16(akc[jt], bq[tt], zz);
#pragma unroll
    for (int jt = 0; jt < 4; ++jt)
      akn[jt] = *(const short8*)(kg + (size_t)(jn + jt * 16 + l15) * DH + quad * 8);
#pragma unroll
    for (int dt = 0; dt < 2; ++dt)
#pragma unroll
      for (int kk = 0; kk < 2; ++kk)
        vbn[dt][kk] = *(const short8*)(vg + (size_t)(dt * 16 + l15) * N_SP + jn + kk * 32 + quad * 8);
#pragma unroll
    for (int tt = 0; tt < 2; ++tt)
#pragma unroll
      for (int jt = 0; jt < 4; ++jt) {
        const float e0 = EXP2(sf[tt][jt][0]);
        const float e1 = EXP2(sf[tt][jt][1]);
        const float e2 = EXP2(sf[tt][jt][2]);
        const float e3 = EXP2(sf[tt][jt][3]);
        lsum[tt] += (e0 + e1) + (e2 + e3);
        uint2 pk; pk.x = pk_bf(e0, e1); pk.y = pk_bf(e2, e3);
        *(uint2*)(prow[tt] + jt * 16 + quad * 4) = pk;
      }
    asm volatile("s_waitcnt lgkmcnt(0)" ::: "memory");  // same-wave P write->read
    short8 pa[2][2];
#pragma unroll
    for (int tt = 0; tt < 2; ++tt)
#pragma unroll
      for (int kk = 0; kk < 2; ++kk) pa[tt][kk] = ld_frag(prow[tt] + kk * 32 + quad * 8);
#pragma unroll
    for (int tt = 0; tt < 2; ++tt)
#pragma unroll
      for (int dt = 0; dt < 2; ++dt) {
        o_acc[tt][dt] = mfma16(pa[tt][0], vbc[dt][0], o_acc[tt][dt]);
        o_acc[tt][dt] = mfma16(pa[tt][1], vbc[dt][1], o_acc[tt][dt]);
      }
  };

  for (int off = 0; off < JH; off += 2 * BJ) {
    body(akA, vbA, akB, vbB, jbeg + ((off + BJ) & (JH - 1)));
    body(akB, vbB, akA, vbA, jbeg + ((off + 2 * BJ) & (JH - 1)));
  }

  // l: reduce over quads; every lane ends with total for i = w*32+tt*16+l15
#pragma unroll
  for (int tt = 0; tt < 2; ++tt) {
    lsum[tt] += __shfl_xor(lsum[tt], 16);
    lsum[tt] += __shfl_xor(lsum[tt], 32);
  }
  if (quad == 0) {
    float* lgp = lg + ((size_t)jh * 16 + bh) * N_SP + i0;
    lgp[w * 32 + l15] = lsum[0];
    lgp[w * 32 + 16 + l15] = lsum[1];
  }
  // raw O -> Osh[d][i] -> coalesced store
#pragma unroll
  for (int tt = 0; tt < 2; ++tt)
#pragma unroll
    for (int dt = 0; dt < 2; ++dt)
#pragma unroll
      for (int r = 0; r < 4; ++r)
        Osh[(dt * 16 + l15) * 132 + w * 32 + tt * 16 + quad * 4 + r] = o_acc[tt][dt][r];
  __syncthreads();
  {
    const int d = t >> 3, ch = t & 7;
    float* dst = Oh + ((size_t)jh * 512 + bh * DH + d) * N_SP + i0 + ch * 16;
    const float* src = Osh + d * 132 + ch * 16;
#pragma unroll
    for (int k2 = 0; k2 < 4; ++k2) *(float4*)(dst + k2 * 4) = *(const float4*)(src + k2 * 4);
  }
}

// ---------------- Kernel 3: combine halves + normalize + output projection ---------
__global__ __launch_bounds__(256) void out_proj_k(
    const float* __restrict__ Oh, const float* __restrict__ lg,
    const float* __restrict__ w, const float* __restrict__ bias,
    float* __restrict__ out) {
  const int t = threadIdx.x;
  const int n0 = blockIdx.x * 1024 + t * 4;
  const int o0 = blockIdx.y * 8;
  const int b = blockIdx.z;
  const float* O0 = Oh + (size_t)(b * HID) * N_SP;
  const float* O1 = O0 + (size_t)512 * N_SP;
  float inv[4][4];
#pragma unroll
  for (int h = 0; h < 4; ++h) {
    const float4 a = *(const float4*)(lg + (size_t)(b * 4 + h) * N_SP + n0);
    const float4 c = *(const float4*)(lg + (size_t)(16 + b * 4 + h) * N_SP + n0);
    inv[h][0] = 1.f / (a.x + c.x); inv[h][1] = 1.f / (a.y + c.y);
    inv[h][2] = 1.f / (a.z + c.z); inv[h][3] = 1.f / (a.w + c.w);
  }
  float acc[8][4];
#pragma unroll
  for (int r = 0; r < 8; ++r)
#pragma unroll
    for (int j = 0; j < 4; ++j) acc[r][j] = 0.f;
  for (int c = 0; c < HID; c += 2) {
    const int h = c >> 5;
    const float4 p0 = *(const float4*)(O0 + (size_t)c * N_SP + n0);
    const float4 q0 = *(const float4*)(O1 + (size_t)c * N_SP + n0);
    const float4 p1 = *(const float4*)(O0 + (size_t)(c + 1) * N_SP + n0);
    const float4 q1 = *(const float4*)(O1 + (size_t)(c + 1) * N_SP + n0);
    float a0j[4] = {(p0.x + q0.x) * inv[h][0], (p0.y + q0.y) * inv[h][1],
                    (p0.z + q0.z) * inv[h][2], (p0.w + q0.w) * inv[h][3]};
    float a1j[4] = {(p1.x + q1.x) * inv[h][0], (p1.y + q1.y) * inv[h][1],
                    (p1.z + q1.z) * inv[h][2], (p1.w + q1.w) * inv[h][3]};
#pragma unroll
    for (int r = 0; r < 8; ++r) {
      const float2 wv = *(const float2*)(w + (size_t)(o0 + r) * HID + c);
#pragma unroll
      for (int j = 0; j < 4; ++j) acc[r][j] += wv.x * a0j[j] + wv.y * a1j[j];
    }
  }
#pragma unroll
  for (int r = 0; r < 8; ++r) {
    const float bv = bias[o0 + r];
    *(float4*)(out + ((size_t)b * C_IN + o0 + r) * N_SP + n0) =
        make_float4(acc[r][0] + bv, acc[r][1] + bv, acc[r][2] + bv, acc[r][3] + bv);
  }
}

extern "C" void kernel_launch(void* const* d_in, const int* in_sizes, int n_in,
                              void* d_out, int out_size, void* d_ws, size_t ws_size,
                              hipStream_t stream) {
  const float* x = (const float*)d_in[0];
  const float* w_qkv = (const float*)d_in[1];
  const float* w_out = (const float*)d_in[2];
  const float* b_out = (const float*)d_in[3];
  float* out = (float*)d_out;

  short* qt = (short*)d_ws;                            // 16*4096*32 bf16 = 4 MB
  short* kt = qt + (size_t)16 * N_SP * DH;             // 4 MB
  short* vt = kt + (size_t)16 * N_SP * DH;             // 4 MB
  float* Oh = (float*)(vt + (size_t)16 * N_SP * DH);   // 2*512*4096 fp32 = 16.8 MB
  float* lg = Oh + (size_t)2 * 512 * N_SP;             // 2*16*4096 fp32 = 512 KB

  qkv_proj_k<<<dim3(16, 12, B_SZ), 256, 0, stream>>>(x, w_qkv, qt, kt, vt);
  attn_k<<<dim3(N_SP / BI, 16, 2), 256, 0, stream>>>(qt, kt, vt, Oh, lg);
  out_proj_k<<<dim3(4, 32, B_SZ), 256, 0, stream>>>(Oh, lg, w_out, b_out, out);
}

// Round 8
// 272.966 us; speedup vs baseline: 1.5142x; 1.5142x over previous
//
#include <hip/hip_runtime.h>
#include <hip/hip_bf16.h>
#include <stdint.h>

#define B_SZ 4
#define C_IN 256
#define N_SP 4096
#define HEADS 4
#define DH 32
#define HID 128

#define BI 128      // queries per block (4 waves x 32)
#define BJ 64       // keys per inner tile
#define NJH 3       // j-split count
#define JHSZ 1408   // keys per split (last split gets 1280)
#define PP 68       // P LDS row pitch in shorts (136 B)

typedef short short4v __attribute__((ext_vector_type(4)));
typedef short short8 __attribute__((ext_vector_type(8)));
typedef float f32x4 __attribute__((ext_vector_type(4)));

#if __has_builtin(__builtin_amdgcn_exp2f)
#define EXP2 __builtin_amdgcn_exp2f
#else
#define EXP2 exp2f
#endif

__device__ __forceinline__ short f2bfs(float f) {  // round-half-up f32->bf16
  return (short)((__float_as_uint(f) + 0x8000u) >> 16);
}
__device__ __forceinline__ uint32_t pk_bf(float a, float b) {  // pack 2 bf16 (a=low)
  uint32_t ua = __float_as_uint(a) + 0x8000u;
  uint32_t ub = __float_as_uint(b) + 0x8000u;
  return (ua >> 16) | (ub & 0xffff0000u);
}
__device__ __forceinline__ float bf_lo(uint32_t u) { return __uint_as_float(u << 16); }
__device__ __forceinline__ float bf_hi(uint32_t u) { return __uint_as_float(u & 0xffff0000u); }
__device__ __forceinline__ short8 ld_frag(const short* p) {  // 8B-aligned 16B LDS read
  short4v a = *(const short4v*)p;
  short4v b = *(const short4v*)(p + 4);
  return __builtin_shufflevector(a, b, 0, 1, 2, 3, 4, 5, 6, 7);
}
__device__ __forceinline__ f32x4 mfma16(short8 a, short8 b, f32x4 c) {
  return __builtin_amdgcn_mfma_f32_16x16x32_bf16(a, b, c, 0, 0, 0);
}

// ---------------- Kernel 1: QKV projection, fused transpose ----------------
// grid (32 nb, 6 og, 4 b). Block: 64 qkv-rows x 128 n.
// Q -> qt[bh][n][32] bf16 (scale*log2e folded), K -> kt[bh][n][32], V -> vt[bh][d][n].
__global__ __launch_bounds__(256) void qkv_proj_k(
    const float* __restrict__ x, const float* __restrict__ w,
    short* __restrict__ qt, short* __restrict__ kt, short* __restrict__ vt) {
  __shared__ short T2[64 * 132];  // [row][n-tile] bf16
  const int t = threadIdx.x;
  const int tn = t & 31, tr = t >> 5;        // tn: n-group (4 cols), tr: row-octet
  const int nb = blockIdx.x, og = blockIdx.y, b = blockIdx.z;
  const int n0 = nb * 128 + tn * 4;
  const int r0 = og * 64 + tr * 8;           // qkv output row base (8 rows)
  const float* xb = x + (size_t)b * C_IN * N_SP + n0;
  float acc[8][4];
#pragma unroll
  for (int r = 0; r < 8; ++r)
#pragma unroll
    for (int j = 0; j < 4; ++j) acc[r][j] = 0.f;
  for (int c = 0; c < C_IN; c += 2) {
    const float4 xa = *(const float4*)(xb + (size_t)c * N_SP);
    const float4 xc = *(const float4*)(xb + (size_t)(c + 1) * N_SP);
    const float xaj[4] = {xa.x, xa.y, xa.z, xa.w};
    const float xcj[4] = {xc.x, xc.y, xc.z, xc.w};
#pragma unroll
    for (int r = 0; r < 8; ++r) {
      const float2 wv = *(const float2*)(w + (size_t)(r0 + r) * C_IN + c);
#pragma unroll
      for (int j = 0; j < 4; ++j) acc[r][j] += wv.x * xaj[j] + wv.y * xcj[j];
    }
  }
  if (og >= 4) {  // V rows: direct [d][n] coalesced 8B stores
    const int d_all = og * 64 - 256 + tr * 8;  // 0..127 = h*32+d
#pragma unroll
    for (int r = 0; r < 8; ++r) {
      const int h = (d_all + r) >> 5, d = (d_all + r) & 31;
      short4v p;
#pragma unroll
      for (int j = 0; j < 4; ++j) p[j] = f2bfs(acc[r][j]);
      *(short4v*)(vt + ((size_t)(b * HEADS + h) * DH + d) * N_SP + n0) = p;
    }
  } else {  // Q/K: LDS [row][n] tile, then chunk-interleaved coalesced [n][d] stores
    const int isK = og >> 1;  // og 0,1 = Q; 2,3 = K
    const float sc = isK ? 1.f : (0.17677669529663687f * 1.4426950408889634f);
#pragma unroll
    for (int r = 0; r < 8; ++r) {
      short4v p;
#pragma unroll
      for (int j = 0; j < 4; ++j) p[j] = f2bfs(acc[r][j] * sc);
      *(short4v*)(T2 + (tr * 8 + r) * 132 + tn * 4) = p;
    }
    __syncthreads();
    const int hbase = (og & 1) * 2;  // first head in this 64-row half-section
#pragma unroll
    for (int k = 0; k < 4; ++k) {
      const int g = t + 256 * k;               // chunk id, 1024 total
      const int hh = g >> 9, rem = g & 511;
      const int n = rem >> 2, dq = rem & 3;    // row n, d-quarter
      short8 v;
#pragma unroll
      for (int e = 0; e < 8; ++e) v[e] = T2[(hh * 32 + dq * 8 + e) * 132 + n];
      short* dst = (isK ? kt : qt) +
                   ((size_t)(b * HEADS + hbase + hh) * N_SP + nb * 128 + n) * DH + dq * 8;
      *(short8*)dst = v;
    }
  }
}

// ---------------- Kernel 2: flash attention, j-split thirds, no-max softmax --------
// grid (32 ib, 16 bh, 3 jh). Unnormalized bf16 O -> Oh[jh][bh*32+d][n], l -> lg[jh][bh][n].
__global__ __launch_bounds__(256, 3) void attn_k(
    const short* __restrict__ qt, const short* __restrict__ kt,
    const short* __restrict__ vt, short* __restrict__ Oh, float* __restrict__ lg) {
  __shared__ short Ps[BI * PP];     // 17408 B, [i][j] bf16, rows owned per-wave
  __shared__ float Osh[DH * 132];   // 16896 B, epilogue transpose
  const int t = threadIdx.x;
  const int lane = t & 63, w = t >> 6;
  const int l15 = lane & 15, quad = lane >> 4;
  const int i0 = blockIdx.x * BI;
  const int bh = blockIdx.y, jh = blockIdx.z;
  const int jbeg = jh * JHSZ;
  const int jend = (jbeg + JHSZ < N_SP) ? (jbeg + JHSZ) : N_SP;
  const short* qg = qt + ((size_t)bh * N_SP + i0) * DH;
  const short* kg = kt + (size_t)bh * N_SP * DH;
  const short* vg = vt + (size_t)bh * DH * N_SP;

  short8 bq[2];
#pragma unroll
  for (int tt = 0; tt < 2; ++tt)
    bq[tt] = *(const short8*)(qg + (size_t)(w * 32 + tt * 16 + l15) * DH + quad * 8);

  const f32x4 zz = {0.f, 0.f, 0.f, 0.f};
  f32x4 o_acc[2][2] = {{zz, zz}, {zz, zz}};  // [tt][dt]
  float lsum[2] = {0.f, 0.f};
  short* prow[2];
#pragma unroll
  for (int tt = 0; tt < 2; ++tt) prow[tt] = Ps + (w * 32 + tt * 16 + l15) * PP;

  short8 akA[4], akB[4], vbA[2][2], vbB[2][2];
#pragma unroll
  for (int jt = 0; jt < 4; ++jt)
    akA[jt] = *(const short8*)(kg + (size_t)(jbeg + jt * 16 + l15) * DH + quad * 8);
#pragma unroll
  for (int dt = 0; dt < 2; ++dt)
#pragma unroll
    for (int kk = 0; kk < 2; ++kk)
      vbA[dt][kk] = *(const short8*)(vg + (size_t)(dt * 16 + l15) * N_SP + jbeg + kk * 32 + quad * 8);

  auto body = [&](const short8 (&akc)[4], const short8 (&vbc)[2][2],
                  short8 (&akn)[4], short8 (&vbn)[2][2], int jn) {
    f32x4 sf[2][4];
#pragma unroll
    for (int tt = 0; tt < 2; ++tt)
#pragma unroll
      for (int jt = 0; jt < 4; ++jt) sf[tt][jt] = mfma16(akc[jt], bq[tt], zz);
#pragma unroll
    for (int jt = 0; jt < 4; ++jt)
      akn[jt] = *(const short8*)(kg + (size_t)(jn + jt * 16 + l15) * DH + quad * 8);
#pragma unroll
    for (int dt = 0; dt < 2; ++dt)
#pragma unroll
      for (int kk = 0; kk < 2; ++kk)
        vbn[dt][kk] = *(const short8*)(vg + (size_t)(dt * 16 + l15) * N_SP + jn + kk * 32 + quad * 8);
#pragma unroll
    for (int tt = 0; tt < 2; ++tt)
#pragma unroll
      for (int jt = 0; jt < 4; ++jt) {
        const float e0 = EXP2(sf[tt][jt][0]);
        const float e1 = EXP2(sf[tt][jt][1]);
        const float e2 = EXP2(sf[tt][jt][2]);
        const float e3 = EXP2(sf[tt][jt][3]);
        lsum[tt] += (e0 + e1) + (e2 + e3);
        uint2 pk; pk.x = pk_bf(e0, e1); pk.y = pk_bf(e2, e3);
        *(uint2*)(prow[tt] + jt * 16 + quad * 4) = pk;
      }
    asm volatile("s_waitcnt lgkmcnt(0)" ::: "memory");  // same-wave P write->read
    short8 pa[2][2];
#pragma unroll
    for (int tt = 0; tt < 2; ++tt)
#pragma unroll
      for (int kk = 0; kk < 2; ++kk) pa[tt][kk] = ld_frag(prow[tt] + kk * 32 + quad * 8);
#pragma unroll
    for (int tt = 0; tt < 2; ++tt)
#pragma unroll
      for (int dt = 0; dt < 2; ++dt) {
        o_acc[tt][dt] = mfma16(pa[tt][0], vbc[dt][0], o_acc[tt][dt]);
        o_acc[tt][dt] = mfma16(pa[tt][1], vbc[dt][1], o_acc[tt][dt]);
      }
  };

  const int npair = (jend - jbeg) >> 7;  // 11 or 10 pairs of 64-key tiles
  int jcur = jbeg;
  for (int p = 0; p < npair; ++p) {
    int jn1 = jcur + BJ;
    body(akA, vbA, akB, vbB, jn1);
    int jn2 = jn1 + BJ; if (jn2 >= jend) jn2 = jbeg;  // last prefetch wraps (discarded)
    body(akB, vbB, akA, vbA, jn2);
    jcur = jn2;
  }

  // l: reduce over quads; store per-i partial sums
#pragma unroll
  for (int tt = 0; tt < 2; ++tt) {
    lsum[tt] += __shfl_xor(lsum[tt], 16);
    lsum[tt] += __shfl_xor(lsum[tt], 32);
  }
  if (quad == 0) {
    float* lgp = lg + ((size_t)jh * 16 + bh) * N_SP + i0;
    lgp[w * 32 + l15] = lsum[0];
    lgp[w * 32 + 16 + l15] = lsum[1];
  }
  // raw O -> Osh[d][i] -> coalesced bf16 store
#pragma unroll
  for (int tt = 0; tt < 2; ++tt)
#pragma unroll
    for (int dt = 0; dt < 2; ++dt)
#pragma unroll
      for (int r = 0; r < 4; ++r)
        Osh[(dt * 16 + l15) * 132 + w * 32 + tt * 16 + quad * 4 + r] = o_acc[tt][dt][r];
  __syncthreads();
  {
    const int d = t >> 3, ch = t & 7;
    short* dst = Oh + ((size_t)jh * 512 + bh * DH + d) * N_SP + i0 + ch * 16;
    const float* src = Osh + d * 132 + ch * 16;
#pragma unroll
    for (int k2 = 0; k2 < 2; ++k2) {
      const float4 a = *(const float4*)(src + k2 * 8);
      const float4 c = *(const float4*)(src + k2 * 8 + 4);
      uint4 o;
      o.x = pk_bf(a.x, a.y); o.y = pk_bf(a.z, a.w);
      o.z = pk_bf(c.x, c.y); o.w = pk_bf(c.z, c.w);
      *(uint4*)(dst + k2 * 8) = o;
    }
  }
}

// ---------------- Kernel 3: combine thirds + normalize + output projection ---------
__global__ __launch_bounds__(256) void out_proj_k(
    const short* __restrict__ Oh, const float* __restrict__ lg,
    const float* __restrict__ w, const float* __restrict__ bias,
    float* __restrict__ out) {
  const int t = threadIdx.x;
  const int n0 = blockIdx.x * 1024 + t * 4;
  const int o0 = blockIdx.y * 8;
  const int b = blockIdx.z;
  float inv[4][4];
#pragma unroll
  for (int h = 0; h < 4; ++h) {
    float s[4] = {0.f, 0.f, 0.f, 0.f};
#pragma unroll
    for (int jh = 0; jh < NJH; ++jh) {
      const float4 a = *(const float4*)(lg + ((size_t)jh * 16 + b * 4 + h) * N_SP + n0);
      s[0] += a.x; s[1] += a.y; s[2] += a.z; s[3] += a.w;
    }
#pragma unroll
    for (int j = 0; j < 4; ++j) inv[h][j] = 1.f / s[j];
  }
  float acc[8][4];
#pragma unroll
  for (int r = 0; r < 8; ++r)
#pragma unroll
    for (int j = 0; j < 4; ++j) acc[r][j] = 0.f;
  for (int c = 0; c < HID; c += 2) {
    const int h = c >> 5;
    float a0j[4] = {0.f, 0.f, 0.f, 0.f}, a1j[4] = {0.f, 0.f, 0.f, 0.f};
#pragma unroll
    for (int jh = 0; jh < NJH; ++jh) {
      const short* base = Oh + ((size_t)jh * 512 + b * HID) * N_SP;
      const uint2 u0 = *(const uint2*)(base + (size_t)c * N_SP + n0);
      const uint2 u1 = *(const uint2*)(base + (size_t)(c + 1) * N_SP + n0);
      a0j[0] += bf_lo(u0.x); a0j[1] += bf_hi(u0.x);
      a0j[2] += bf_lo(u0.y); a0j[3] += bf_hi(u0.y);
      a1j[0] += bf_lo(u1.x); a1j[1] += bf_hi(u1.x);
      a1j[2] += bf_lo(u1.y); a1j[3] += bf_hi(u1.y);
    }
#pragma unroll
    for (int j = 0; j < 4; ++j) { a0j[j] *= inv[h][j]; a1j[j] *= inv[h][j]; }
#pragma unroll
    for (int r = 0; r < 8; ++r) {
      const float2 wv = *(const float2*)(w + (size_t)(o0 + r) * HID + c);
#pragma unroll
      for (int j = 0; j < 4; ++j) acc[r][j] += wv.x * a0j[j] + wv.y * a1j[j];
    }
  }
#pragma unroll
  for (int r = 0; r < 8; ++r) {
    const float bv = bias[o0 + r];
    *(float4*)(out + ((size_t)b * C_IN + o0 + r) * N_SP + n0) =
        make_float4(acc[r][0] + bv, acc[r][1] + bv, acc[r][2] + bv, acc[r][3] + bv);
  }
}

extern "C" void kernel_launch(void* const* d_in, const int* in_sizes, int n_in,
                              void* d_out, int out_size, void* d_ws, size_t ws_size,
                              hipStream_t stream) {
  const float* x = (const float*)d_in[0];
  const float* w_qkv = (const float*)d_in[1];
  const float* w_out = (const float*)d_in[2];
  const float* b_out = (const float*)d_in[3];
  float* out = (float*)d_out;

  short* qt = (short*)d_ws;                            // 16*4096*32 bf16 = 4 MB
  short* kt = qt + (size_t)16 * N_SP * DH;             // 4 MB
  short* vt = kt + (size_t)16 * N_SP * DH;             // 4 MB
  short* Oh = vt + (size_t)16 * N_SP * DH;             // 3*512*4096 bf16 = 12.6 MB
  float* lg = (float*)(Oh + (size_t)NJH * 512 * N_SP); // 3*16*4096 fp32 = 786 KB

  qkv_proj_k<<<dim3(32, 6, B_SZ), 256, 0, stream>>>(x, w_qkv, qt, kt, vt);
  attn_k<<<dim3(N_SP / BI, 16, NJH), 256, 0, stream>>>(qt, kt, vt, Oh, lg);
  out_proj_k<<<dim3(4, 32, B_SZ), 256, 0, stream>>>(Oh, lg, w_out, b_out, out);
}